// Round 14
// baseline (1055.832 us; speedup 1.0000x reference)
//
#include <hip/hip_runtime.h>
#include <hip/hip_fp16.h>

#define TLEN  1024
#define HN    64
#define LOG2E 1.4426950408889634f

// R13 post-mortem: fdot2 ran SLOWER than fp32 fma (1006 vs 837 us) with ~3x
// the modeled issue count -- strong evidence v_dot2_f32_f16 is emulated on
// gfx950 (ISA ref lists no dot2). R14 swaps in __hfma2 -> v_pk_fma_f16
// (documented VOP3P packed op): 2 MACs/instr, f16 accumulate. Precision
// kept safe by accumulating ONLY the 16-term w.h partials in f16 (halves of
// one __half2 = the {j, j+32} k-split), converting to fp32 BEFORE bias/x
// add and the exchange. Rest = R13's proven structure: 2-wave k-split,
// 64 packed weight regs/lane (allocates clean at VGPR~88), h broadcast via
// readlane of hp = pk(h, h>>32), dbuf float4 LDS exchange, ONE barrier,
// redundant activations/update both waves; wave 1 owns x.W_ih (fp32 fma)
// + FC ring + coalesced store; wave 0 owns biases.

#define FOR16(X) \
    X(0) X(1) X(2) X(3) X(4) X(5) X(6) X(7) \
    X(8) X(9) X(10) X(11) X(12) X(13) X(14) X(15)

__global__ __launch_bounds__(128)
__attribute__((amdgpu_waves_per_eu(2, 2)))
void lstm_pk(const float* __restrict__ x,      // [B, T, 4]
             const float* __restrict__ W_ih,   // [256, 4]
             const float* __restrict__ W_hh,   // [256, 64]
             const float* __restrict__ b_ih,   // [256]
             const float* __restrict__ b_hh,   // [256]
             const float* __restrict__ W_fc,   // [1, 64]
             const float* __restrict__ b_fc,   // [1]
             float* __restrict__ out)          // [B, T]
{
    const int tid = threadIdx.x;
    const int g   = tid & 63;        // hidden unit 0..63
    const int w   = tid >> 6;        // wave 0/1 = k-half
    const int b   = blockIdx.x;
    const int jb  = 16 * w;          // readlane base

    __shared__ __align__(16) float4 px[2][2][HN];   // partial exchange, dbuf
    __shared__ float ring[64][65];                  // FC partials (bank-free)

    const float* wr_i = W_hh + (0 * HN + g) * HN;
    const float* wr_f = W_hh + (1 * HN + g) * HN;
    const float* wr_g = W_hh + (2 * HN + g) * HN;
    const float* wr_o = W_hh + (3 * HN + g) * HN;

    // ---- 64 packed weight pairs {k=jb+m, k=jb+m+32} as raw ints ----
    // NOTE: weights NOT pre-scaled by log2e here -- f16 accumulation wants
    // raw magnitudes; log2e applied in fp32 after the exchange.
#define DECL(m) int qi##m, qf##m, qg##m, qo##m;
    FOR16(DECL)
#undef DECL

#define PK2(lo, hi) __builtin_bit_cast(int, __builtin_amdgcn_cvt_pkrtz((lo), (hi)))
#define LOADW(m) \
    qi##m = PK2(wr_i[jb + m], wr_i[jb + m + 32]); \
    qf##m = PK2(wr_f[jb + m], wr_f[jb + m + 32]); \
    qg##m = PK2(wr_g[jb + m], wr_g[jb + m + 32]); \
    qo##m = PK2(wr_o[jb + m], wr_o[jb + m + 32]); \
    asm volatile("" : "+v"(qi##m), "+v"(qf##m), "+v"(qg##m), "+v"(qo##m));
    FOR16(LOADW)
#undef LOADW
#undef PK2

    // wave 0: biases; wave 1: fp32 x-weights (4/gate)
    float bias_i = 0.f, bias_f = 0.f, bias_g = 0.f, bias_o = 0.f;
    float4 wxi = {0,0,0,0}, wxf = {0,0,0,0}, wxg = {0,0,0,0}, wxo = {0,0,0,0};
    if (w == 0) {
        bias_i = b_ih[0 * HN + g] + b_hh[0 * HN + g];
        bias_f = b_ih[1 * HN + g] + b_hh[1 * HN + g];
        bias_g = b_ih[2 * HN + g] + b_hh[2 * HN + g];
        bias_o = b_ih[3 * HN + g] + b_hh[3 * HN + g];
    } else {
        wxi = *(const float4*)(W_ih + (0 * HN + g) * 4);
        wxf = *(const float4*)(W_ih + (1 * HN + g) * 4);
        wxg = *(const float4*)(W_ih + (2 * HN + g) * 4);
        wxo = *(const float4*)(W_ih + (3 * HN + g) * 4);
    }
    const float wfc = W_fc[g];
    const float bfc = b_fc[0];

    const float* xb = x   + (size_t)b * TLEN * 4;
    float*       ob = out + (size_t)b * TLEN;

    float h = 0.0f, c = 0.0f;
    int hp = 0;   // packed {h[j], h[j+32]} per lane j (h starts 0)
    float4 xt = {0, 0, 0, 0};
    if (w == 1) xt = *(const float4*)(xb);

    const __half2 z2 = __float2half2_rn(0.0f);

    for (int t = 0; t < TLEN; ++t) {
        float4 xn = {0, 0, 0, 0};
        if (w == 1) {
            int tn = t + 1; if (tn >= TLEN) tn = TLEN - 1;
            xn = *(const float4*)(xb + (size_t)tn * 4);   // prefetch
        }

        // ---- w.h partials: 16 readlane + 64 v_pk_fma_f16 ----
        // acc halves = independent 16-term sums over {jb..jb+15} and +32.
        __half2 acci = z2, accf = z2, accg = z2, acco = z2;
#define MAC(m) { \
        int hj = __builtin_amdgcn_readlane(hp, jb + (m)); \
        __half2 hh = __builtin_bit_cast(__half2, hj); \
        acci = __hfma2(__builtin_bit_cast(__half2, qi##m), hh, acci); \
        accf = __hfma2(__builtin_bit_cast(__half2, qf##m), hh, accf); \
        accg = __hfma2(__builtin_bit_cast(__half2, qg##m), hh, accg); \
        acco = __hfma2(__builtin_bit_cast(__half2, qo##m), hh, acco); }
        FOR16(MAC)
#undef MAC

        // fp32 finish: fold halves + bias (w0) / x.W_ih (w1)
        float pi, pf, pg, po;
        if (w == 0) {
            pi = bias_i + __low2float(acci) + __high2float(acci);
            pf = bias_f + __low2float(accf) + __high2float(accf);
            pg = bias_g + __low2float(accg) + __high2float(accg);
            po = bias_o + __low2float(acco) + __high2float(acco);
        } else {
            pi = __low2float(acci) + __high2float(acci)
               + wxi.x * xt.x + wxi.y * xt.y + wxi.z * xt.z + wxi.w * xt.w;
            pf = __low2float(accf) + __high2float(accf)
               + wxf.x * xt.x + wxf.y * xt.y + wxf.z * xt.z + wxf.w * xt.w;
            pg = __low2float(accg) + __high2float(accg)
               + wxg.x * xt.x + wxg.y * xt.y + wxg.z * xt.z + wxg.w * xt.w;
            po = __low2float(acco) + __high2float(acco)
               + wxo.x * xt.x + wxo.y * xt.y + wxo.z * xt.z + wxo.w * xt.w;
        }

        // ---- exchange (dbuf, 1 barrier); commutative add -> identical h ----
        px[t & 1][w][g] = make_float4(pi, pf, pg, po);
        __syncthreads();
        float4 oth = px[t & 1][1 - w][g];
        float ai = (pi + oth.x) * LOG2E;
        float af = (pf + oth.y) * LOG2E;
        float ag = (pg + oth.z) * (2.0f * LOG2E);
        float ao = (po + oth.w) * LOG2E;

        // ---- activations: sigmoid/tanh via exp2+rcp ----
        float si = __builtin_amdgcn_rcpf(1.0f + __builtin_amdgcn_exp2f(-ai));
        float sf = __builtin_amdgcn_rcpf(1.0f + __builtin_amdgcn_exp2f(-af));
        float tg = 1.0f - 2.0f * __builtin_amdgcn_rcpf(
                                     1.0f + __builtin_amdgcn_exp2f(ag));
        float so = __builtin_amdgcn_rcpf(1.0f + __builtin_amdgcn_exp2f(-ao));

        c = sf * c + si * tg;
        float th = 1.0f - 2.0f * __builtin_amdgcn_rcpf(
                       1.0f + __builtin_amdgcn_exp2f(c * (2.0f * LOG2E)));
        h = so * th;

        // repack h pairs for next step's readlane broadcast (both waves)
        float h_hi = __shfl_down(h, 32, 64);
        hp = __builtin_bit_cast(int, __builtin_amdgcn_cvt_pkrtz(h, h_hi));

        // ---- wave 1: x advance + FC ring + periodic coalesced store ----
        if (w == 1) {
            xt = xn;
            ring[t & 63][g] = h * wfc;
            if ((t & 63) == 63) {   // own-wave data: lgkmcnt orders w->r
                float s0 = 0.f, s1 = 0.f, s2 = 0.f, s3 = 0.f;
#pragma unroll
                for (int k = 0; k < HN; k += 4) {
                    s0 += ring[g][k];
                    s1 += ring[g][k + 1];
                    s2 += ring[g][k + 2];
                    s3 += ring[g][k + 3];
                }
                ob[(t - 63) + g] = (s0 + s1) + (s2 + s3) + bfc;
            }
        }
    }
}

extern "C" void kernel_launch(void* const* d_in, const int* in_sizes, int n_in,
                              void* d_out, int out_size, void* d_ws, size_t ws_size,
                              hipStream_t stream) {
    const float* x    = (const float*)d_in[0];
    const float* W_ih = (const float*)d_in[1];
    const float* W_hh = (const float*)d_in[2];
    const float* b_ih = (const float*)d_in[3];
    const float* b_hh = (const float*)d_in[4];
    const float* W_fc = (const float*)d_in[5];
    const float* b_fc = (const float*)d_in[6];
    float* out = (float*)d_out;

    const int B = in_sizes[0] / (TLEN * 4);   // 1024
    lstm_pk<<<dim3(B), dim3(128), 0, stream>>>(
        x, W_ih, W_hh, b_ih, b_hh, W_fc, b_fc, out);
}